// Round 16
// baseline (184.867 us; speedup 1.0000x reference)
//
#include <hip/hip_runtime.h>
#include <math.h>
#include <stdint.h>

#define NNODE 100000
#define NREL 2000
#define NEDGE 600000
#define DIM 128
#define OUTC 384   // DIM*(DEPTH+1)
#define LOG2E 1.4426950408889634f

#define RELU_BLOCKS 12500                      // NNODE*32/256
#define PRE_BLOCKS 500                         // NREL*64/256
#define ROW_BLOCKS ((NNODE + 1 + 255) / 256)   // 391

typedef float f32x2 __attribute__((ext_vector_type(2)));
typedef unsigned u32x4 __attribute__((ext_vector_type(4)));

__device__ __forceinline__ float wave_sum(float v) {
#pragma unroll
    for (int off = 32; off > 0; off >>= 1)
        v += __shfl_xor(v, off, 64);
    return v;
}

// sum across each 16-lane group, all lanes get the sum; pure-VALU DPP
// (quad_perm xor1, xor2, then row_ror:4, row_ror:8 -- all within a 16-lane row)
__device__ __forceinline__ float dpp_sum16(float x) {
    x += __int_as_float(__builtin_amdgcn_mov_dpp(__float_as_int(x), 0xB1, 0xF, 0xF, true));
    x += __int_as_float(__builtin_amdgcn_mov_dpp(__float_as_int(x), 0x4E, 0xF, 0xF, true));
    x += __int_as_float(__builtin_amdgcn_mov_dpp(__float_as_int(x), 0x124, 0xF, 0xF, true));
    x += __int_as_float(__builtin_amdgcn_mov_dpp(__float_as_int(x), 0x128, 0xF, 0xF, true));
    return x;
}

// round-to-nearest-even f32 -> bf16 bits
__device__ __forceinline__ unsigned short f2bf(float f) {
    unsigned b = __float_as_uint(f);
    return (unsigned short)((b + 0x7fffu + ((b >> 16) & 1u)) >> 16);
}
__device__ __forceinline__ unsigned pack2(float f0, float f1) {
    return (unsigned)f2bf(f0) | ((unsigned)f2bf(f1) << 16);
}
__device__ __forceinline__ f32x2 bf2(unsigned u) {
    f32x2 r;
    r.x = __uint_as_float(u << 16);
    r.y = __uint_as_float(u & 0xffff0000u);
    return r;
}

// Fused setup, region-partitioned by blockIdx:
//  [0, RELU_BLOCKS)      relu(features) -> d_out f32 + bf16 mirror + layer-0 neigh dot
//  [.., +PRE_BLOCKS)     per-relation ||rel||^2, rdB/rdC both layers, rel bf16 mirror
//  [.., +ROW_BLOCKS)     CSR row_ptr by binary search over sorted adj_src
__global__ void k_setup(const float* __restrict__ f, const float* __restrict__ rel,
                        const float* __restrict__ attn, const int* __restrict__ adj_src,
                        float* __restrict__ out, unsigned short* __restrict__ fm,
                        unsigned short* __restrict__ relm,
                        float* __restrict__ relnorm2, float* __restrict__ rdB,
                        float* __restrict__ rdC,
                        float* __restrict__ nd0, int* __restrict__ row_ptr) {
    int b = blockIdx.x;
    if (b < RELU_BLOCKS) {
        int idx = b * 256 + threadIdx.x;
        int n = idx >> 5;   // 32 float4 per row
        int q = idx & 31;
        float4 v = reinterpret_cast<const float4*>(f + (size_t)n * DIM)[q];
        v.x = fmaxf(v.x, 0.f); v.y = fmaxf(v.y, 0.f);
        v.z = fmaxf(v.z, 0.f); v.w = fmaxf(v.w, 0.f);
        reinterpret_cast<float4*>(out + (size_t)n * OUTC)[q] = v;
        uint2 p;
        p.x = pack2(v.x, v.y);
        p.y = pack2(v.z, v.w);
        reinterpret_cast<uint2*>(fm + (size_t)n * DIM)[q] = p;
        // layer-0 per-node neighbor dot with attn part B (32-lane segmented reduce)
        float4 bb = reinterpret_cast<const float4*>(attn + DIM)[q];
        float pb = v.x * bb.x + v.y * bb.y + v.z * bb.z + v.w * bb.w;
#pragma unroll
        for (int off = 1; off <= 16; off <<= 1)
            pb += __shfl_xor(pb, off, 64);
        if (q == 0) nd0[n] = pb * LOG2E;
    } else if (b < RELU_BLOCKS + PRE_BLOCKS) {
        int wid = (b - RELU_BLOCKS) * 4 + (threadIdx.x >> 6);  // < NREL exactly
        int lane = threadIdx.x & 63;
        float2 v = reinterpret_cast<const float2*>(rel + (size_t)wid * DIM)[lane];
        reinterpret_cast<unsigned*>(relm + (size_t)wid * DIM)[lane] = pack2(v.x, v.y);
        float2 b0 = reinterpret_cast<const float2*>(attn + DIM)[lane];
        float2 c0 = reinterpret_cast<const float2*>(attn + 2 * DIM)[lane];
        float2 b1 = reinterpret_cast<const float2*>(attn + 3 * DIM + DIM)[lane];
        float2 c1 = reinterpret_cast<const float2*>(attn + 3 * DIM + 2 * DIM)[lane];
        float n2  = wave_sum(v.x * v.x + v.y * v.y);
        float pb0 = wave_sum(v.x * b0.x + v.y * b0.y);
        float pc0 = wave_sum(v.x * c0.x + v.y * c0.y);
        float pb1 = wave_sum(v.x * b1.x + v.y * b1.y);
        float pc1 = wave_sum(v.x * c1.x + v.y * c1.y);
        if (lane == 0) {
            relnorm2[wid] = n2;
            rdB[wid] = pb0;        rdC[wid] = pc0;
            rdB[NREL + wid] = pb1; rdC[NREL + wid] = pc1;
        }
    } else {
        int n = (b - RELU_BLOCKS - PRE_BLOCKS) * 256 + threadIdx.x;
        if (n <= NNODE) {
            int lo = 0, hi = NEDGE;
            while (lo < hi) {
                int mid = (lo + hi) >> 1;
                if (adj_src[mid] < n) lo = mid + 1; else hi = mid;
            }
            row_ptr[n] = lo;
        }
    }
}

// 4 nodes per wave, one 16-lane group per node; serial edge loop with depth-2
// pipeline (A/B/C rotate); DPP 16-lane dot reduce; log2-domain softmax without
// max subtraction. fm row gathers are nontemporal (25.6 MB random set cannot
// fit 4 MiB/XCD L2 -- keep its lines out so relm/metadata stay resident).
template<int WRITE_NEXT>
__global__ void k_gat(const unsigned short* __restrict__ fin_m,
                      float* __restrict__ fout,
                      unsigned short* __restrict__ fout_m,
                      const unsigned short* __restrict__ relm,
                      const int* __restrict__ adj_dst, const int* __restrict__ sp_rel,
                      const float* __restrict__ sp_val, const float* __restrict__ relnorm2,
                      const float* __restrict__ rdB, const float* __restrict__ rdC,
                      const float* __restrict__ ndpre,   // log2-scaled neigh dots
                      const int* __restrict__ row_ptr,
                      float* __restrict__ nd_n,
                      const float* __restrict__ akB_next) {
    int wv = (blockIdx.x * blockDim.x + threadIdx.x) >> 6;
    int lane = threadIdx.x & 63;
    int g = lane >> 4, gl = lane & 15;
    int node = wv * 4 + g;
    if (node >= NNODE) return;
    int e0 = row_ptr[node], e1 = row_ptr[node + 1];

    f32x2 acc0 = 0.f, acc1 = 0.f, acc2 = 0.f, acc3 = 0.f;
    float s = 0.f;

    auto ld = [&](int ee, u32x4& fb_, u32x4& rb_, float& ab_, float& qb_, float& q2_) {
        fb_ = 0; rb_ = 0;
        ab_ = 0.f; qb_ = 0.f; q2_ = 0.f;
        if (ee < e1) {
            int dst = adj_dst[ee];
            int r = sp_rel[ee];
            // fm gather nontemporal (no L2 reuse possible); relm stays cacheable
            fb_ = __builtin_nontemporal_load(
                reinterpret_cast<const u32x4*>(fin_m + (unsigned)((dst << 7) + (gl << 3))));
            rb_ = *reinterpret_cast<const u32x4*>(relm + (unsigned)((r << 7) + (gl << 3)));
            float v = sp_val[ee];
            float sc = v * rsqrtf(fmaxf(v * v * relnorm2[r], 1e-12f));
            q2_ = 2.f * sc * sc;
            qb_ = q2_ * LOG2E * rdB[r];
            ab_ = ndpre[dst] + sc * LOG2E * rdC[r];
        }
    };

    u32x4 fbA, rbA, fbB, rbB;
    float abA, qbA, q2A, abB, qbB, q2B;
    int e = e0;
    ld(e, fbA, rbA, abA, qbA, q2A);
    ld(e + 1, fbB, rbB, abB, qbB, q2B);
    while (e < e1) {
        u32x4 fbC, rbC;
        float abC, qbC, q2C;
        ld(e + 2, fbC, rbC, abC, qbC, q2C);   // depth-2 prefetch

        f32x2 f0 = bf2(fbA.x), f1 = bf2(fbA.y), f2 = bf2(fbA.z), f3 = bf2(fbA.w);
        f32x2 r0 = bf2(rbA.x), r1 = bf2(rbA.y), r2 = bf2(rbA.z), r3 = bf2(rbA.w);
        f32x2 d2 = f0 * r0;
        d2 += f1 * r1;
        d2 += f2 * r2;
        d2 += f3 * r3;
        float dot = dpp_sum16(d2.x + d2.y);
        float w = __builtin_exp2f(abA - dot * qbA);   // log2-domain, no max-sub
        float k2 = dot * q2A;
        s += w;
        acc0 += w * (f0 - k2 * r0);
        acc1 += w * (f1 - k2 * r1);
        acc2 += w * (f2 - k2 * r2);
        acc3 += w * (f3 - k2 * r3);

        fbA = fbB; rbA = rbB; abA = abB; qbA = qbB; q2A = q2B;
        fbB = fbC; rbB = rbC; abB = abC; qbB = qbC; q2B = q2C;
        ++e;
    }

    float inv = (s > 0.f) ? 1.f / s : 0.f;
    float o[8];
    o[0] = fmaxf(acc0.x * inv, 0.f); o[1] = fmaxf(acc0.y * inv, 0.f);
    o[2] = fmaxf(acc1.x * inv, 0.f); o[3] = fmaxf(acc1.y * inv, 0.f);
    o[4] = fmaxf(acc2.x * inv, 0.f); o[5] = fmaxf(acc2.y * inv, 0.f);
    o[6] = fmaxf(acc3.x * inv, 0.f); o[7] = fmaxf(acc3.y * inv, 0.f);
    float4* op = reinterpret_cast<float4*>(fout + (unsigned)(node * OUTC + gl * 8));
    op[0] = make_float4(o[0], o[1], o[2], o[3]);
    op[1] = make_float4(o[4], o[5], o[6], o[7]);
    if (WRITE_NEXT) {
        uint4 mw;
        mw.x = pack2(o[0], o[1]); mw.y = pack2(o[2], o[3]);
        mw.z = pack2(o[4], o[5]); mw.w = pack2(o[6], o[7]);
        *reinterpret_cast<uint4*>(fout_m + (unsigned)((node << 7) + (gl << 3))) = mw;
        // next-layer neigh dot from the fresh output (16-lane DPP reduce)
        const float4* aB = reinterpret_cast<const float4*>(akB_next) + gl * 2;
        float4 b0 = aB[0], b1 = aB[1];
        float pb = o[0] * b0.x + o[1] * b0.y + o[2] * b0.z + o[3] * b0.w
                 + o[4] * b1.x + o[5] * b1.y + o[6] * b1.z + o[7] * b1.w;
        pb = dpp_sum16(pb);
        if (gl == 0) nd_n[node] = pb * LOG2E;
    }
}

extern "C" void kernel_launch(void* const* d_in, const int* in_sizes, int n_in,
                              void* d_out, int out_size, void* d_ws, size_t ws_size,
                              hipStream_t stream) {
    const float* features = (const float*)d_in[0];
    const float* rel_emb  = (const float*)d_in[1];
    const float* sp_val   = (const float*)d_in[2];
    const float* attn     = (const float*)d_in[3];
    const int*   adj_src  = (const int*)d_in[4];
    const int*   adj_dst  = (const int*)d_in[5];
    const int*   sp_rel   = (const int*)d_in[6];
    // d_in[7] = sp_row = arange(E) -> identity segment_sum, unused
    float* out = (float*)d_out;

    char* p = (char*)d_ws;
    unsigned short* mir0 = (unsigned short*)p; p += (size_t)NNODE * DIM * 2;
    unsigned short* mir1 = (unsigned short*)p; p += (size_t)NNODE * DIM * 2;
    unsigned short* relm = (unsigned short*)p; p += (size_t)NREL * DIM * 2;
    float* nd0      = (float*)p; p += (size_t)NNODE * 4;
    float* nd1      = (float*)p; p += (size_t)NNODE * 4;
    float* relnorm2 = (float*)p; p += (size_t)NREL * 4;
    float* rdB      = (float*)p; p += (size_t)2 * NREL * 4;
    float* rdC      = (float*)p; p += (size_t)2 * NREL * 4;
    int*   row_ptr  = (int*)p;   p += (size_t)(NNODE + 1) * 4;

    k_setup<<<RELU_BLOCKS + PRE_BLOCKS + ROW_BLOCKS, 256, 0, stream>>>(
        features, rel_emb, attn, adj_src, out, mir0, relm,
        relnorm2, rdB, rdC, nd0, row_ptr);

    int gat_blocks = (NNODE / 4 * 64) / 256;  // 6250
    const float* akB1 = attn + 3 * DIM + DIM;

    k_gat<1><<<gat_blocks, 256, 0, stream>>>(
        mir0, out + DIM, mir1, relm, adj_dst, sp_rel, sp_val, relnorm2,
        rdB, rdC, nd0, row_ptr, nd1, akB1);
    k_gat<0><<<gat_blocks, 256, 0, stream>>>(
        mir1, out + 2 * DIM, (unsigned short*)nullptr, relm, adj_dst, sp_rel,
        sp_val, relnorm2, rdB + NREL, rdC + NREL, nd1, row_ptr,
        (float*)nullptr, (const float*)nullptr);
}

// Round 17
// 135.538 us; speedup vs baseline: 1.3639x; 1.3639x over previous
//
#include <hip/hip_runtime.h>
#include <math.h>
#include <stdint.h>

#define NNODE 100000
#define NREL 2000
#define NEDGE 600000
#define DIM 128
#define OUTC 384   // DIM*(DEPTH+1)
#define LOG2E 1.4426950408889634f

#define RELU_BLOCKS 12500                      // NNODE*32/256
#define PRE_BLOCKS 500                         // NREL*64/256
#define ROW_BLOCKS ((NNODE + 1 + 255) / 256)   // 391

typedef float f32x2 __attribute__((ext_vector_type(2)));

__device__ __forceinline__ float wave_sum(float v) {
#pragma unroll
    for (int off = 32; off > 0; off >>= 1)
        v += __shfl_xor(v, off, 64);
    return v;
}

// sum across each 16-lane group, all lanes get the sum; pure-VALU DPP
// (quad_perm xor1, xor2, then row_ror:4, row_ror:8 -- all within a 16-lane row)
__device__ __forceinline__ float dpp_sum16(float x) {
    x += __int_as_float(__builtin_amdgcn_mov_dpp(__float_as_int(x), 0xB1, 0xF, 0xF, true));
    x += __int_as_float(__builtin_amdgcn_mov_dpp(__float_as_int(x), 0x4E, 0xF, 0xF, true));
    x += __int_as_float(__builtin_amdgcn_mov_dpp(__float_as_int(x), 0x124, 0xF, 0xF, true));
    x += __int_as_float(__builtin_amdgcn_mov_dpp(__float_as_int(x), 0x128, 0xF, 0xF, true));
    return x;
}

// round-to-nearest-even f32 -> bf16 bits
__device__ __forceinline__ unsigned short f2bf(float f) {
    unsigned b = __float_as_uint(f);
    return (unsigned short)((b + 0x7fffu + ((b >> 16) & 1u)) >> 16);
}
__device__ __forceinline__ unsigned pack2(float f0, float f1) {
    return (unsigned)f2bf(f0) | ((unsigned)f2bf(f1) << 16);
}
__device__ __forceinline__ f32x2 bf2(unsigned u) {
    f32x2 r;
    r.x = __uint_as_float(u << 16);
    r.y = __uint_as_float(u & 0xffff0000u);
    return r;
}

// Fused setup, region-partitioned by blockIdx:
//  [0, RELU_BLOCKS)      relu(features) -> d_out f32 + bf16 mirror + layer-0 neigh dot
//  [.., +PRE_BLOCKS)     per-relation ||rel||^2, rdB/rdC both layers, rel bf16 mirror
//  [.., +ROW_BLOCKS)     CSR row_ptr by binary search over sorted adj_src
__global__ void k_setup(const float* __restrict__ f, const float* __restrict__ rel,
                        const float* __restrict__ attn, const int* __restrict__ adj_src,
                        float* __restrict__ out, unsigned short* __restrict__ fm,
                        unsigned short* __restrict__ relm,
                        float* __restrict__ relnorm2, float* __restrict__ rdB,
                        float* __restrict__ rdC,
                        float* __restrict__ nd0, int* __restrict__ row_ptr) {
    int b = blockIdx.x;
    if (b < RELU_BLOCKS) {
        int idx = b * 256 + threadIdx.x;
        int n = idx >> 5;   // 32 float4 per row
        int q = idx & 31;
        float4 v = reinterpret_cast<const float4*>(f + (size_t)n * DIM)[q];
        v.x = fmaxf(v.x, 0.f); v.y = fmaxf(v.y, 0.f);
        v.z = fmaxf(v.z, 0.f); v.w = fmaxf(v.w, 0.f);
        reinterpret_cast<float4*>(out + (size_t)n * OUTC)[q] = v;
        uint2 p;
        p.x = pack2(v.x, v.y);
        p.y = pack2(v.z, v.w);
        reinterpret_cast<uint2*>(fm + (size_t)n * DIM)[q] = p;
        // layer-0 per-node neighbor dot with attn part B (32-lane segmented reduce)
        float4 bb = reinterpret_cast<const float4*>(attn + DIM)[q];
        float pb = v.x * bb.x + v.y * bb.y + v.z * bb.z + v.w * bb.w;
#pragma unroll
        for (int off = 1; off <= 16; off <<= 1)
            pb += __shfl_xor(pb, off, 64);
        if (q == 0) nd0[n] = pb * LOG2E;
    } else if (b < RELU_BLOCKS + PRE_BLOCKS) {
        int wid = (b - RELU_BLOCKS) * 4 + (threadIdx.x >> 6);  // < NREL exactly
        int lane = threadIdx.x & 63;
        float2 v = reinterpret_cast<const float2*>(rel + (size_t)wid * DIM)[lane];
        reinterpret_cast<unsigned*>(relm + (size_t)wid * DIM)[lane] = pack2(v.x, v.y);
        float2 b0 = reinterpret_cast<const float2*>(attn + DIM)[lane];
        float2 c0 = reinterpret_cast<const float2*>(attn + 2 * DIM)[lane];
        float2 b1 = reinterpret_cast<const float2*>(attn + 3 * DIM + DIM)[lane];
        float2 c1 = reinterpret_cast<const float2*>(attn + 3 * DIM + 2 * DIM)[lane];
        float n2  = wave_sum(v.x * v.x + v.y * v.y);
        float pb0 = wave_sum(v.x * b0.x + v.y * b0.y);
        float pc0 = wave_sum(v.x * c0.x + v.y * c0.y);
        float pb1 = wave_sum(v.x * b1.x + v.y * b1.y);
        float pc1 = wave_sum(v.x * c1.x + v.y * c1.y);
        if (lane == 0) {
            relnorm2[wid] = n2;
            rdB[wid] = pb0;        rdC[wid] = pc0;
            rdB[NREL + wid] = pb1; rdC[NREL + wid] = pc1;
        }
    } else {
        int n = (b - RELU_BLOCKS - PRE_BLOCKS) * 256 + threadIdx.x;
        if (n <= NNODE) {
            int lo = 0, hi = NEDGE;
            while (lo < hi) {
                int mid = (lo + hi) >> 1;
                if (adj_src[mid] < n) lo = mid + 1; else hi = mid;
            }
            row_ptr[n] = lo;
        }
    }
}

// 4 nodes per wave, one 16-lane group per node; serial edge loop with depth-2
// pipeline (A/B/C rotate); DPP 16-lane dot reduce; log2-domain softmax without
// max subtraction. Per-edge scalars computed in-loop from sequential streams +
// L1-resident tables (no precompute passes). All accesses cacheable (R12/R16:
// nontemporal hints hurt in both directions).
template<int WRITE_NEXT>
__global__ void k_gat(const unsigned short* __restrict__ fin_m,
                      float* __restrict__ fout,
                      unsigned short* __restrict__ fout_m,
                      const unsigned short* __restrict__ relm,
                      const int* __restrict__ adj_dst, const int* __restrict__ sp_rel,
                      const float* __restrict__ sp_val, const float* __restrict__ relnorm2,
                      const float* __restrict__ rdB, const float* __restrict__ rdC,
                      const float* __restrict__ ndpre,   // log2-scaled neigh dots
                      const int* __restrict__ row_ptr,
                      float* __restrict__ nd_n,
                      const float* __restrict__ akB_next) {
    int wv = (blockIdx.x * blockDim.x + threadIdx.x) >> 6;
    int lane = threadIdx.x & 63;
    int g = lane >> 4, gl = lane & 15;
    int node = wv * 4 + g;
    if (node >= NNODE) return;
    int e0 = row_ptr[node], e1 = row_ptr[node + 1];

    f32x2 acc0 = 0.f, acc1 = 0.f, acc2 = 0.f, acc3 = 0.f;
    float s = 0.f;

    auto ld = [&](int ee, uint4& fb_, uint4& rb_, float& ab_, float& qb_, float& q2_) {
        fb_ = make_uint4(0, 0, 0, 0); rb_ = make_uint4(0, 0, 0, 0);
        ab_ = 0.f; qb_ = 0.f; q2_ = 0.f;
        if (ee < e1) {
            int dst = adj_dst[ee];
            int r = sp_rel[ee];
            // issue the two row gathers first; scalar math fills their shadow
            fb_ = *reinterpret_cast<const uint4*>(fin_m + (unsigned)((dst << 7) + (gl << 3)));
            rb_ = *reinterpret_cast<const uint4*>(relm + (unsigned)((r << 7) + (gl << 3)));
            float v = sp_val[ee];
            float sc = v * rsqrtf(fmaxf(v * v * relnorm2[r], 1e-12f));
            q2_ = 2.f * sc * sc;
            qb_ = q2_ * LOG2E * rdB[r];
            ab_ = ndpre[dst] + sc * LOG2E * rdC[r];
        }
    };

    uint4 fbA, rbA, fbB, rbB;
    float abA, qbA, q2A, abB, qbB, q2B;
    int e = e0;
    ld(e, fbA, rbA, abA, qbA, q2A);
    ld(e + 1, fbB, rbB, abB, qbB, q2B);
    while (e < e1) {
        uint4 fbC, rbC;
        float abC, qbC, q2C;
        ld(e + 2, fbC, rbC, abC, qbC, q2C);   // depth-2 prefetch

        f32x2 f0 = bf2(fbA.x), f1 = bf2(fbA.y), f2 = bf2(fbA.z), f3 = bf2(fbA.w);
        f32x2 r0 = bf2(rbA.x), r1 = bf2(rbA.y), r2 = bf2(rbA.z), r3 = bf2(rbA.w);
        f32x2 d2 = f0 * r0;
        d2 += f1 * r1;
        d2 += f2 * r2;
        d2 += f3 * r3;
        float dot = dpp_sum16(d2.x + d2.y);
        float w = __builtin_exp2f(abA - dot * qbA);   // log2-domain, no max-sub
        float k2 = dot * q2A;
        s += w;
        acc0 += w * (f0 - k2 * r0);
        acc1 += w * (f1 - k2 * r1);
        acc2 += w * (f2 - k2 * r2);
        acc3 += w * (f3 - k2 * r3);

        fbA = fbB; rbA = rbB; abA = abB; qbA = qbB; q2A = q2B;
        fbB = fbC; rbB = rbC; abB = abC; qbB = qbC; q2B = q2C;
        ++e;
    }

    float inv = (s > 0.f) ? 1.f / s : 0.f;
    float o[8];
    o[0] = fmaxf(acc0.x * inv, 0.f); o[1] = fmaxf(acc0.y * inv, 0.f);
    o[2] = fmaxf(acc1.x * inv, 0.f); o[3] = fmaxf(acc1.y * inv, 0.f);
    o[4] = fmaxf(acc2.x * inv, 0.f); o[5] = fmaxf(acc2.y * inv, 0.f);
    o[6] = fmaxf(acc3.x * inv, 0.f); o[7] = fmaxf(acc3.y * inv, 0.f);
    float4* op = reinterpret_cast<float4*>(fout + (unsigned)(node * OUTC + gl * 8));
    op[0] = make_float4(o[0], o[1], o[2], o[3]);
    op[1] = make_float4(o[4], o[5], o[6], o[7]);
    if (WRITE_NEXT) {
        uint4 mw;
        mw.x = pack2(o[0], o[1]); mw.y = pack2(o[2], o[3]);
        mw.z = pack2(o[4], o[5]); mw.w = pack2(o[6], o[7]);
        *reinterpret_cast<uint4*>(fout_m + (unsigned)((node << 7) + (gl << 3))) = mw;
        // next-layer neigh dot from the fresh output (16-lane DPP reduce)
        const float4* aB = reinterpret_cast<const float4*>(akB_next) + gl * 2;
        float4 b0 = aB[0], b1 = aB[1];
        float pb = o[0] * b0.x + o[1] * b0.y + o[2] * b0.z + o[3] * b0.w
                 + o[4] * b1.x + o[5] * b1.y + o[6] * b1.z + o[7] * b1.w;
        pb = dpp_sum16(pb);
        if (gl == 0) nd_n[node] = pb * LOG2E;
    }
}

extern "C" void kernel_launch(void* const* d_in, const int* in_sizes, int n_in,
                              void* d_out, int out_size, void* d_ws, size_t ws_size,
                              hipStream_t stream) {
    const float* features = (const float*)d_in[0];
    const float* rel_emb  = (const float*)d_in[1];
    const float* sp_val   = (const float*)d_in[2];
    const float* attn     = (const float*)d_in[3];
    const int*   adj_src  = (const int*)d_in[4];
    const int*   adj_dst  = (const int*)d_in[5];
    const int*   sp_rel   = (const int*)d_in[6];
    // d_in[7] = sp_row = arange(E) -> identity segment_sum, unused
    float* out = (float*)d_out;

    char* p = (char*)d_ws;
    unsigned short* mir0 = (unsigned short*)p; p += (size_t)NNODE * DIM * 2;
    unsigned short* mir1 = (unsigned short*)p; p += (size_t)NNODE * DIM * 2;
    unsigned short* relm = (unsigned short*)p; p += (size_t)NREL * DIM * 2;
    float* nd0      = (float*)p; p += (size_t)NNODE * 4;
    float* nd1      = (float*)p; p += (size_t)NNODE * 4;
    float* relnorm2 = (float*)p; p += (size_t)NREL * 4;
    float* rdB      = (float*)p; p += (size_t)2 * NREL * 4;
    float* rdC      = (float*)p; p += (size_t)2 * NREL * 4;
    int*   row_ptr  = (int*)p;   p += (size_t)(NNODE + 1) * 4;

    k_setup<<<RELU_BLOCKS + PRE_BLOCKS + ROW_BLOCKS, 256, 0, stream>>>(
        features, rel_emb, attn, adj_src, out, mir0, relm,
        relnorm2, rdB, rdC, nd0, row_ptr);

    int gat_blocks = (NNODE / 4 * 64) / 256;  // 6250
    const float* akB1 = attn + 3 * DIM + DIM;

    k_gat<1><<<gat_blocks, 256, 0, stream>>>(
        mir0, out + DIM, mir1, relm, adj_dst, sp_rel, sp_val, relnorm2,
        rdB, rdC, nd0, row_ptr, nd1, akB1);
    k_gat<0><<<gat_blocks, 256, 0, stream>>>(
        mir1, out + 2 * DIM, (unsigned short*)nullptr, relm, adj_dst, sp_rel,
        sp_val, relnorm2, rdB + NREL, rdC + NREL, nd1, row_ptr,
        (float*)nullptr, (const float*)nullptr);
}